// Round 3
// baseline (789.969 us; speedup 1.0000x reference)
//
#include <hip/hip_runtime.h>

#define DIM 64
#define NF 14
#define NOUT 105
#define NN 8192
#define NE 16384
#define NB 256
#define NS 2048
#define NJ 1024
#define KTOT 4160   // 4096 bilinear + 64 bias-fold rows
#define KSPLIT 8

// ---- internal bf16 arena element offsets ----
#define C_X      0
#define C_EA     114688
#define C_L0W    180224
#define C_L0B    181120
#define C_NW1    181184
#define C_NB1    181440
#define C_NW2    181504
#define C_NB2    443648
#define C_CRT    447744
#define C_CB     451840
#define C_GWIH   451904
#define C_GWHH   464192
#define C_GBIH   476480
#define C_GBHH   476672
#define C_SW1    476864
#define C_SB1    480960
#define C_SW2    481024
#define C_SB2    487744
#define C_JW1    487856
#define C_JB1    491952
#define C_JW2    492016
#define C_JB2    492080
#define C_S2IH   492088
#define C_S2HH   492344
#define C_LOW    492600
#define C_LOB    492856
#define C_TOT    492864

typedef float f32x4 __attribute__((ext_vector_type(4)));
typedef short bf16x8 __attribute__((ext_vector_type(8)));

__device__ __forceinline__ float bf2f(unsigned short u){
  union { unsigned int i; float f; } v; v.i = ((unsigned int)u) << 16; return v.f;
}
__device__ __forceinline__ unsigned short f2bf(float f){
  union { float f; unsigned int i; } v; v.f = f;
  unsigned int x = v.i;
  return (unsigned short)((x + 0x7FFFu + ((x >> 16) & 1u)) >> 16);
}
__device__ __forceinline__ float sigm(float x){ return 1.f / (1.f + __expf(-x)); }
__device__ __forceinline__ float tanh_f(float x){
  x = fminf(10.f, fmaxf(-10.f, x));
  float e = __expf(2.f * x);
  return (e - 1.f) / (e + 1.f);
}
__device__ __forceinline__ float lrelu(float x){ return x > 0.f ? x : 0.01f * x; }

__device__ __forceinline__ float wred_sum(float v){
  #pragma unroll
  for (int off = 32; off > 0; off >>= 1) v += __shfl_xor(v, off, 64);
  return v;
}
__device__ __forceinline__ float wred_max(float v){
  #pragma unroll
  for (int off = 32; off > 0; off >>= 1) v = fmaxf(v, __shfl_xor(v, off, 64));
  return v;
}

// ---------------- dtype detect + convert ----------------

__global__ void k_detect(const unsigned short* __restrict__ ea, int* __restrict__ flag){
  __shared__ int cnt;
  if (threadIdx.x == 0) cnt = 0;
  __syncthreads();
  int c = 0;
  for (int i = threadIdx.x; i < 8192; i += 256) c += (ea[2*i] >> 15) & 1;
  atomicAdd(&cnt, c);
  __syncthreads();
  if (threadIdx.x == 0) *flag = (cnt > 100) ? 1 : 0;  // 1 => inputs are fp32
}

struct CvtArgs {
  const void* src[26];
  int n[26];
  int off[26];
};

__global__ void k_cvt(CvtArgs a, const int* __restrict__ flag, unsigned short* __restrict__ dst){
  bool f32 = (*flag != 0);
  int gid = blockIdx.x * blockDim.x + threadIdx.x, gs = gridDim.x * blockDim.x;
  #pragma unroll 1
  for (int j = 0; j < 26; ++j){
    const void* s = a.src[j];
    int n = a.n[j], o = a.off[j];
    for (int i = gid; i < n; i += gs)
      dst[o + i] = f32 ? f2bf(((const float*)s)[i]) : ((const unsigned short*)s)[i];
  }
}

// ---------------- setup kernels ----------------

__global__ void k_deg(const int* __restrict__ ei, float* __restrict__ deg){
  int e = blockIdx.x * blockDim.x + threadIdx.x;
  if (e < NE) atomicAdd(&deg[ei[NE + e]], 1.0f);
}

__global__ void k_lin0(const unsigned short* __restrict__ cvt,
                       float* __restrict__ actF, unsigned short* __restrict__ actB){
  const unsigned short* x = cvt + C_X;
  const unsigned short* w = cvt + C_L0W;
  const unsigned short* b = cvt + C_L0B;
  int idx = blockIdx.x * blockDim.x + threadIdx.x;
  int n = idx >> 6, d = idx & 63;
  float acc = bf2f(b[d]);
  #pragma unroll
  for (int f = 0; f < NF; ++f) acc += bf2f(x[n*NF + f]) * bf2f(w[f*DIM + d]);
  float v = lrelu(acc);
  actF[idx] = v; actB[idx] = f2bf(v);
}

__global__ void k_u(const unsigned short* __restrict__ cvt, unsigned short* __restrict__ u){
  const unsigned short* ea = cvt + C_EA;
  const unsigned short* w  = cvt + C_NW1;
  const unsigned short* b  = cvt + C_NB1;
  int idx = blockIdx.x * blockDim.x + threadIdx.x;
  int e = idx >> 6, d = idx & 63;
  float acc = bf2f(b[d]);
  #pragma unroll
  for (int f = 0; f < 4; ++f) acc += bf2f(ea[e*4 + f]) * bf2f(w[f*DIM + d]);
  u[idx] = f2bf(lrelu(acc));
}

// W2rT[o][k]: k<4096 -> net_w2[(k>>6)*4096 + (k&63)*64 + o]; k>=4096 -> b2[(k-4096)*64 + o]
__global__ void k_w2r(const unsigned short* __restrict__ cvt, unsigned short* __restrict__ w2rt){
  const unsigned short* w2 = cvt + C_NW2;
  const unsigned short* b2 = cvt + C_NB2;
  int t = blockIdx.x * blockDim.x + threadIdx.x;   // 64*4160
  int o = t / KTOT, k = t - o * KTOT;
  unsigned short v = (k < 4096) ? w2[(k >> 6) * 4096 + (k & 63) * 64 + o]
                                : b2[(k - 4096) * 64 + o];
  w2rt[t] = v;
}

__global__ void k_prep(const unsigned short* __restrict__ cvt,
                       unsigned short* __restrict__ crt, unsigned short* __restrict__ btg,
                       float* __restrict__ cbg, float* __restrict__ qv){
  const unsigned short* cr  = cvt + C_CRT;
  const unsigned short* wih = cvt + C_GWIH;
  const unsigned short* whh = cvt + C_GWHH;
  const unsigned short* bih = cvt + C_GBIH;
  const unsigned short* bhh = cvt + C_GBHH;
  const unsigned short* s2sbih = cvt + C_S2IH;
  const unsigned short* s2sbhh = cvt + C_S2HH;
  int tid = threadIdx.x;
  for (int t = tid; t < 4096; t += 256){ int n = t & 63, k = t >> 6; crt[n*64 + k] = cr[k*64 + n]; }
  for (int t = tid; t < 32768; t += 256){
    int nidx = t >> 7, kidx = t & 127;
    int g = nidx >> 6, d = nidx & 63, ki = kidx & 63;
    unsigned short v = 0;
    if (kidx < 64){
      if (g == 0) v = wih[ki*192 + d];
      else if (g == 1) v = wih[ki*192 + 64 + d];
      else if (g == 2) v = wih[ki*192 + 128 + d];
    } else {
      if (g == 0) v = whh[ki*192 + d];
      else if (g == 1) v = whh[ki*192 + 64 + d];
      else if (g == 3) v = whh[ki*192 + 128 + d];
    }
    btg[nidx*128 + kidx] = v;
  }
  if (tid < 256){
    int g = tid >> 6, d = tid & 63;
    float v;
    if (g == 0) v = bf2f(bih[d]) + bf2f(bhh[d]);
    else if (g == 1) v = bf2f(bih[64 + d]) + bf2f(bhh[64 + d]);
    else if (g == 2) v = bf2f(bih[128 + d]);
    else v = bf2f(bhh[128 + d]);
    cbg[tid] = v;
  }
  if (tid < 64){
    float gi = bf2f(s2sbih[tid])       + bf2f(s2sbhh[tid]);
    float gg = bf2f(s2sbih[128 + tid]) + bf2f(s2sbhh[128 + tid]);
    float go = bf2f(s2sbih[192 + tid]) + bf2f(s2sbhh[192 + tid]);
    float c = sigm(gi) * tanh_f(gg);
    qv[tid] = sigm(go) * tanh_f(c);
  }
}

// ---------------- fused per-iteration message GEMM ----------------
// msg[e][o] = sum_k A[e][k] * W2rT[o][k],  A[e][d*64+i] = z_e[d]*a_e[i],
// A[e][4096+i] = a_e[i] (bias rows). Grid: (NE/256, KSPLIT); atomicAdd partials.

__global__ __launch_bounds__(256) void k_msgf(const unsigned short* __restrict__ actB,
                                              const unsigned short* __restrict__ z,
                                              const unsigned short* __restrict__ w2rt,
                                              const int* __restrict__ ei,
                                              float* __restrict__ agg){
  __shared__ __align__(16) unsigned short sz[256 * 8];
  int w = threadIdx.x >> 6, lane = threadIdx.x & 63;
  int lm = lane & 15, q8 = (lane >> 4) * 8, rq = (lane >> 4) * 4;
  int e0 = blockIdx.x * 256;
  int s  = blockIdx.y;
  {
    int t = threadIdx.x;
    *(uint4*)&sz[t * 8] = *(const uint4*)&z[(size_t)(e0 + t) * 64 + s * 8];
  }
  __syncthreads();

  uint4 apack[4][2];
  #pragma unroll
  for (int mt = 0; mt < 4; ++mt){
    int src = ei[e0 + w*64 + mt*16 + lm];
    apack[mt][0] = *(const uint4*)&actB[(size_t)src * 64 + q8];
    apack[mt][1] = *(const uint4*)&actB[(size_t)src * 64 + 32 + q8];
  }

  f32x4 acc[4][4];
  #pragma unroll
  for (int mt = 0; mt < 4; ++mt)
    #pragma unroll
    for (int nt = 0; nt < 4; ++nt) acc[mt][nt] = (f32x4){0.f, 0.f, 0.f, 0.f};

  int kk0 = s * 16;
  int nk = (s == KSPLIT - 1) ? 18 : 16;   // last split also takes the 2 bias chunks
  for (int c = 0; c < nk; ++c){
    int kk = kk0 + c;
    bf16x8 bfr[4];
    #pragma unroll
    for (int nt = 0; nt < 4; ++nt)
      bfr[nt] = *(const bf16x8*)&w2rt[(size_t)(nt*16 + lm) * KTOT + kk*32 + q8];
    #pragma unroll
    for (int mt = 0; mt < 4; ++mt){
      float zf = 1.0f;
      if (kk < 128){
        int erow = w*64 + mt*16 + lm;
        zf = bf2f(sz[erow * 8 + ((kk >> 1) & 7)]);
      }
      uint4 ap = apack[mt][kk & 1];
      bf16x8 af;
      #pragma unroll
      for (int h = 0; h < 4; ++h){
        unsigned int dw = ((const unsigned int*)&ap)[h];
        float flo = __uint_as_float(dw << 16) * zf;
        float fhi = __uint_as_float(dw & 0xFFFF0000u) * zf;
        unsigned int pk = ((unsigned int)f2bf(flo)) | (((unsigned int)f2bf(fhi)) << 16);
        ((unsigned int*)&af)[h] = pk;
      }
      #pragma unroll
      for (int nt = 0; nt < 4; ++nt)
        acc[mt][nt] = __builtin_amdgcn_mfma_f32_16x16x32_bf16(af, bfr[nt], acc[mt][nt], 0, 0, 0);
    }
  }

  #pragma unroll
  for (int mt = 0; mt < 4; ++mt){
    int dstv[4];
    #pragma unroll
    for (int r = 0; r < 4; ++r) dstv[r] = ei[NE + e0 + w*64 + mt*16 + rq + r];
    #pragma unroll
    for (int nt = 0; nt < 4; ++nt)
      #pragma unroll
      for (int r = 0; r < 4; ++r)
        atomicAdd(&agg[(size_t)dstv[r] * 64 + nt*16 + lm], acc[mt][nt][r]);
  }
}

// ---------------- per-iteration: fused conv_root + GRU ----------------

__global__ __launch_bounds__(64) void k_gru(const unsigned short* __restrict__ actB_in,
                                            const float* __restrict__ actF_in,
                                            const float* __restrict__ agg, const float* __restrict__ deg,
                                            const unsigned short* __restrict__ crt,
                                            const unsigned short* __restrict__ cvt,
                                            const unsigned short* __restrict__ btg,
                                            const float* __restrict__ cbg,
                                            float* __restrict__ actF_out, unsigned short* __restrict__ actB_out){
  const unsigned short* cbias = cvt + C_CB;
  __shared__ __align__(16) unsigned short s_m[16*64];
  int lane = threadIdx.x;
  int lm = lane & 15, q8 = (lane >> 4) * 8, rq = (lane >> 4) * 4;
  int r0 = blockIdx.x * 16;
  f32x4 am[4];
  #pragma unroll
  for (int nt = 0; nt < 4; ++nt) am[nt] = (f32x4){0.f, 0.f, 0.f, 0.f};
  #pragma unroll
  for (int kk = 0; kk < 2; ++kk){
    bf16x8 a = *(const bf16x8*)&actB_in[(size_t)(r0 + lm)*64 + kk*32 + q8];
    #pragma unroll
    for (int nt = 0; nt < 4; ++nt){
      bf16x8 b = *(const bf16x8*)&crt[(size_t)(nt*16 + lm)*64 + kk*32 + q8];
      am[nt] = __builtin_amdgcn_mfma_f32_16x16x32_bf16(a, b, am[nt], 0, 0, 0);
    }
  }
  #pragma unroll
  for (int nt = 0; nt < 4; ++nt){
    int col = nt*16 + lm;
    float cb = bf2f(cbias[col]);
    #pragma unroll
    for (int r = 0; r < 4; ++r){
      int row = r0 + rq + r;
      float dg = fmaxf(deg[row], 1.f);
      float v = am[nt][r] + agg[row*64 + col] / dg + cb;
      s_m[(rq + r)*64 + col] = f2bf(lrelu(v));
    }
  }
  __syncthreads();
  f32x4 g[16];
  #pragma unroll
  for (int nt = 0; nt < 16; ++nt) g[nt] = (f32x4){0.f, 0.f, 0.f, 0.f};
  #pragma unroll
  for (int kk = 0; kk < 4; ++kk){
    bf16x8 a;
    if (kk < 2) a = *(const bf16x8*)&s_m[lm*64 + kk*32 + q8];
    else        a = *(const bf16x8*)&actB_in[(size_t)(r0 + lm)*64 + (kk - 2)*32 + q8];
    #pragma unroll
    for (int nt = 0; nt < 16; ++nt){
      bf16x8 b = *(const bf16x8*)&btg[(size_t)(nt*16 + lm)*128 + kk*32 + q8];
      g[nt] = __builtin_amdgcn_mfma_f32_16x16x32_bf16(a, b, g[nt], 0, 0, 0);
    }
  }
  #pragma unroll
  for (int dt = 0; dt < 4; ++dt){
    int d = dt*16 + lm;
    float cb_r = cbg[d], cb_z = cbg[64 + d], cb_n = cbg[128 + d], cb_h = cbg[192 + d];
    #pragma unroll
    for (int r = 0; r < 4; ++r){
      int row = r0 + rq + r;
      float rr = sigm(g[dt][r] + cb_r);
      float zz = sigm(g[4 + dt][r] + cb_z);
      float nn = tanh_f(g[8 + dt][r] + cb_n + rr * (g[12 + dt][r] + cb_h));
      float ho = actF_in[(size_t)row*64 + d];
      float hn2 = (1.f - zz) * nn + zz * ho;
      actF_out[(size_t)row*64 + d] = hn2;
      actB_out[(size_t)row*64 + d] = f2bf(hn2);
    }
  }
}

// ---------------- final heads ----------------

__global__ void k_edot(const float* __restrict__ act, const float* __restrict__ qv,
                       float* __restrict__ evec){
  int w = threadIdx.x >> 6, lane = threadIdx.x & 63;
  int n = blockIdx.x * 4 + w;
  float p = act[(size_t)n*64 + lane] * qv[lane];
  p = wred_sum(p);
  if (lane == 0) evec[n] = p;
}

__device__ __forceinline__ int lower_bound_batch(const int* b, int val){
  int lo = 0, hi = NN;
  while (lo < hi){ int mid = (lo + hi) >> 1; if (b[mid] < val) lo = mid + 1; else hi = mid; }
  return lo;
}

__device__ __forceinline__ void store_out(void* outp, const int* flag, size_t idx, float v){
  if (*flag) ((float*)outp)[idx] = v;
  else       ((unsigned short*)outp)[idx] = f2bf(v);
}

__global__ __launch_bounds__(64) void k_graph(const float* __restrict__ act, const float* __restrict__ evec,
                                              const int* __restrict__ batch, const float* __restrict__ qv,
                                              const unsigned short* __restrict__ cvt,
                                              const int* __restrict__ flag,
                                              void* __restrict__ outp){
  const unsigned short* lw = cvt + C_LOW;
  const unsigned short* lb = cvt + C_LOB;
  int b = blockIdx.x, lane = threadIdx.x;
  int lo = lower_bound_batch(batch, b);
  int hi = lower_bound_batch(batch, b + 1);
  float em = -3.4e38f;
  for (int n = lo + lane; n < hi; n += 64) em = fmaxf(em, evec[n]);
  em = wred_max(em);
  float sm = 0.f;
  for (int n = lo + lane; n < hi; n += 64) sm += __expf(evec[n] - em);
  float denom = wred_sum(sm);
  float rp = 0.f;
  for (int n = lo; n < hi; ++n) rp += __expf(evec[n] - em) * act[(size_t)n*64 + lane];
  if (hi > lo && denom > 0.f) rp /= denom;
  float s0 = qv[lane]*bf2f(lw[lane*2])     + rp*bf2f(lw[(64 + lane)*2]);
  float s1 = qv[lane]*bf2f(lw[lane*2 + 1]) + rp*bf2f(lw[(64 + lane)*2 + 1]);
  s0 = wred_sum(s0); s1 = wred_sum(s1);
  if (lane == 0){
    store_out(outp, flag, b*2,     s0 + bf2f(lb[0]));
    store_out(outp, flag, b*2 + 1, s1 + bf2f(lb[1]));
  }
}

__global__ __launch_bounds__(256) void k_stem(const float* __restrict__ act, const int* __restrict__ sidx,
                                              const unsigned short* __restrict__ cvt,
                                              const int* __restrict__ flag,
                                              void* __restrict__ outp){
  const unsigned short* w1 = cvt + C_SW1;
  const unsigned short* b1 = cvt + C_SB1;
  const unsigned short* w2 = cvt + C_SW2;
  const unsigned short* b2 = cvt + C_SB2;
  __shared__ float sa[4][64], st[4][64];
  int w = threadIdx.x >> 6, lane = threadIdx.x & 63;
  int s = blockIdx.x * 4 + w;
  int a = sidx[s];
  sa[w][lane] = act[(size_t)a*64 + lane];
  __syncthreads();
  float t = bf2f(b1[lane]);
  #pragma unroll 8
  for (int i = 0; i < 64; ++i) t += sa[w][i] * bf2f(w1[i*64 + lane]);
  st[w][lane] = lrelu(t);
  __syncthreads();
  size_t base = 512 + (size_t)s * NOUT;
  float v = bf2f(b2[lane]);
  #pragma unroll 8
  for (int d = 0; d < 64; ++d) v += st[w][d] * bf2f(w2[d*NOUT + lane]);
  store_out(outp, flag, base + lane, v);
  int o2 = 64 + lane;
  if (o2 < NOUT){
    float v2 = bf2f(b2[o2]);
    #pragma unroll 8
    for (int d = 0; d < 64; ++d) v2 += st[w][d] * bf2f(w2[d*NOUT + o2]);
    store_out(outp, flag, base + o2, v2);
  }
}

__global__ __launch_bounds__(256) void k_jbond(const float* __restrict__ act, const int* __restrict__ jidx,
                                               const unsigned short* __restrict__ cvt,
                                               const int* __restrict__ flag,
                                               void* __restrict__ outp){
  const unsigned short* w1 = cvt + C_JW1;
  const unsigned short* b1 = cvt + C_JB1;
  const unsigned short* w2 = cvt + C_JW2;
  const unsigned short* b2 = cvt + C_JB2;
  __shared__ float a0[4][64], a1[4][64];
  int w = threadIdx.x >> 6, lane = threadIdx.x & 63;
  int j = blockIdx.x * 4 + w;
  int i0 = jidx[j*2], i1 = jidx[j*2 + 1];
  a0[w][lane] = act[(size_t)i0*64 + lane];
  a1[w][lane] = act[(size_t)i1*64 + lane];
  __syncthreads();
  float t0 = bf2f(b1[lane]), t1 = t0;
  #pragma unroll 8
  for (int i = 0; i < 64; ++i){
    float wv = bf2f(w1[i*64 + lane]);
    t0 += a0[w][i] * wv;
    t1 += a1[w][i] * wv;
  }
  t0 = lrelu(t0); t1 = lrelu(t1);
  float p = (t0 + t1) * bf2f(w2[lane]);
  p = wred_sum(p);
  if (lane == 0) store_out(outp, flag, 512 + (size_t)NS*NOUT + j, 0.5f * p + bf2f(b2[0]));
}

// ---------------- launcher ----------------

extern "C" void kernel_launch(void* const* d_in, const int* in_sizes, int n_in,
                              void* d_out, int out_size, void* d_ws, size_t ws_size,
                              hipStream_t stream){
  (void)in_sizes; (void)n_in; (void)out_size; (void)ws_size;
  const int* edge_index = (const int*)d_in[2];
  const int* batch      = (const int*)d_in[3];
  const int* stem_idx   = (const int*)d_in[4];
  const int* jbond_idx  = (const int*)d_in[5];

  char* ws = (char*)d_ws;
  size_t off = 0;
  auto alloc = [&](size_t bytes) -> void* {
    void* p = ws + off; off += (bytes + 255) & ~(size_t)255; return p;
  };
  unsigned short* cvt  = (unsigned short*)alloc((size_t)C_TOT * 2);       // ~1 MB
  unsigned short* w2rt = (unsigned short*)alloc((size_t)64 * KTOT * 2);   // 0.53 MB
  unsigned short* z_bf = (unsigned short*)alloc((size_t)NE * 64 * 2);     // 2 MB
  float* actF0 = (float*)alloc((size_t)NN * 64 * 4);
  float* actF1 = (float*)alloc((size_t)NN * 64 * 4);
  unsigned short* actB0 = (unsigned short*)alloc((size_t)NN * 64 * 2);
  unsigned short* actB1 = (unsigned short*)alloc((size_t)NN * 64 * 2);
  float* agg  = (float*)alloc((size_t)NN * 64 * 4);
  float* deg  = (float*)alloc(NN * 4);
  unsigned short* crt = (unsigned short*)alloc(64 * 64 * 2);
  unsigned short* btg = (unsigned short*)alloc(256 * 128 * 2);
  float* cbg  = (float*)alloc(256 * 4);
  float* qv   = (float*)alloc(64 * 4);
  float* evec = (float*)alloc(NN * 4);
  int* flag   = (int*)alloc(256);

  k_detect<<<1, 256, 0, stream>>>((const unsigned short*)d_in[1], flag);

  CvtArgs ca;
  const int srcIdx[26] = {0,1,6,7,8,9,10,11,12,13,14,15,16,17,18,19,20,21,22,23,24,25,28,29,30,31};
  const int ns[26]  = {114688,65536,896,64,256,64,262144,4096,4096,64,12288,12288,192,192,
                       4096,64,6720,105,4096,64,64,1,256,256,256,2};
  const int ofs[26] = {C_X,C_EA,C_L0W,C_L0B,C_NW1,C_NB1,C_NW2,C_NB2,C_CRT,C_CB,C_GWIH,C_GWHH,
                       C_GBIH,C_GBHH,C_SW1,C_SB1,C_SW2,C_SB2,C_JW1,C_JB1,C_JW2,C_JB2,
                       C_S2IH,C_S2HH,C_LOW,C_LOB};
  for (int j = 0; j < 26; ++j){ ca.src[j] = d_in[srcIdx[j]]; ca.n[j] = ns[j]; ca.off[j] = ofs[j]; }
  k_cvt<<<512, 256, 0, stream>>>(ca, flag, cvt);

  hipMemsetAsync(deg, 0, NN * sizeof(float), stream);
  k_deg<<<NE/256, 256, 0, stream>>>(edge_index, deg);
  k_lin0<<<NN*DIM/256, 256, 0, stream>>>(cvt, actF0, actB0);
  k_u<<<NE*DIM/256, 256, 0, stream>>>(cvt, z_bf);
  k_w2r<<<64*KTOT/256, 256, 0, stream>>>(cvt, w2rt);
  k_prep<<<1, 256, 0, stream>>>(cvt, crt, btg, cbg, qv);

  for (int t = 0; t < 6; ++t){
    const float* aF_in  = (t & 1) ? actF1 : actF0;
    float* aF_out       = (t & 1) ? actF0 : actF1;
    const unsigned short* aB_in = (t & 1) ? actB1 : actB0;
    unsigned short* aB_out      = (t & 1) ? actB0 : actB1;
    hipMemsetAsync(agg, 0, (size_t)NN * 64 * sizeof(float), stream);
    k_msgf<<<dim3(NE/256, KSPLIT), 256, 0, stream>>>(aB_in, z_bf, w2rt, edge_index, agg);
    k_gru<<<NN/16, 64, 0, stream>>>(aB_in, aF_in, agg, deg, crt, cvt, btg, cbg,
                                    aF_out, aB_out);
  }
  k_edot<<<NN/4, 256, 0, stream>>>(actF0, qv, evec);
  k_graph<<<NB, 64, 0, stream>>>(actF0, evec, batch, qv, cvt, flag, d_out);
  k_stem<<<NS/4, 256, 0, stream>>>(actF0, stem_idx, cvt, flag, d_out);
  k_jbond<<<NJ/4, 256, 0, stream>>>(actF0, jbond_idx, cvt, flag, d_out);
}

// Round 4
// 445.095 us; speedup vs baseline: 1.7748x; 1.7748x over previous
//
#include <hip/hip_runtime.h>

#define DIM 64
#define NF 14
#define NOUT 105
#define NN 8192
#define NE 16384
#define NB 256
#define NS 2048
#define NJ 1024
#define KTOT 4160   // 4096 bilinear + 64 bias-fold rows (fallback path)
#define KSPLIT 8

// ---- internal bf16 arena element offsets ----
#define C_X      0
#define C_EA     114688
#define C_L0W    180224
#define C_L0B    181120
#define C_NW1    181184
#define C_NB1    181440
#define C_NW2    181504
#define C_NB2    443648
#define C_CRT    447744
#define C_CB     451840
#define C_GWIH   451904
#define C_GWHH   464192
#define C_GBIH   476480
#define C_GBHH   476672
#define C_SW1    476864
#define C_SB1    480960
#define C_SW2    481024
#define C_SB2    487744
#define C_JW1    487856
#define C_JB1    491952
#define C_JW2    492016
#define C_JB2    492080
#define C_S2IH   492088
#define C_S2HH   492344
#define C_LOW    492600
#define C_LOB    492856
#define C_TOT    492864

typedef float f32x4 __attribute__((ext_vector_type(4)));
typedef short bf16x8 __attribute__((ext_vector_type(8)));

__device__ __forceinline__ float bf2f(unsigned short u){
  union { unsigned int i; float f; } v; v.i = ((unsigned int)u) << 16; return v.f;
}
__device__ __forceinline__ unsigned short f2bf(float f){
  union { float f; unsigned int i; } v; v.f = f;
  unsigned int x = v.i;
  return (unsigned short)((x + 0x7FFFu + ((x >> 16) & 1u)) >> 16);
}
__device__ __forceinline__ float sigm(float x){ return 1.f / (1.f + __expf(-x)); }
__device__ __forceinline__ float tanh_f(float x){
  x = fminf(10.f, fmaxf(-10.f, x));
  float e = __expf(2.f * x);
  return (e - 1.f) / (e + 1.f);
}
__device__ __forceinline__ float lrelu(float x){ return x > 0.f ? x : 0.01f * x; }

__device__ __forceinline__ float wred_sum(float v){
  #pragma unroll
  for (int off = 32; off > 0; off >>= 1) v += __shfl_xor(v, off, 64);
  return v;
}
__device__ __forceinline__ float wred_max(float v){
  #pragma unroll
  for (int off = 32; off > 0; off >>= 1) v = fmaxf(v, __shfl_xor(v, off, 64));
  return v;
}

// ---------------- dtype detect + convert ----------------

__global__ void k_detect(const unsigned short* __restrict__ ea, int* __restrict__ flag){
  __shared__ int cnt;
  if (threadIdx.x == 0) cnt = 0;
  __syncthreads();
  int c = 0;
  for (int i = threadIdx.x; i < 8192; i += 256) c += (ea[2*i] >> 15) & 1;
  atomicAdd(&cnt, c);
  __syncthreads();
  if (threadIdx.x == 0) *flag = (cnt > 100) ? 1 : 0;  // 1 => inputs are fp32
}

struct CvtArgs {
  const void* src[26];
  int n[26];
  int off[26];
};

__global__ void k_cvt(CvtArgs a, const int* __restrict__ flag, unsigned short* __restrict__ dst){
  bool f32 = (*flag != 0);
  int gid = blockIdx.x * blockDim.x + threadIdx.x, gs = gridDim.x * blockDim.x;
  #pragma unroll 1
  for (int j = 0; j < 26; ++j){
    const void* s = a.src[j];
    int n = a.n[j], o = a.off[j];
    for (int i = gid; i < n; i += gs)
      dst[o + i] = f32 ? f2bf(((const float*)s)[i]) : ((const unsigned short*)s)[i];
  }
}

// ---------------- setup kernels ----------------

__global__ void k_deg(const int* __restrict__ ei, float* __restrict__ deg){
  int e = blockIdx.x * blockDim.x + threadIdx.x;
  if (e < NE) atomicAdd(&deg[ei[NE + e]], 1.0f);
}

__global__ void k_lin0(const unsigned short* __restrict__ cvt,
                       float* __restrict__ actF, unsigned short* __restrict__ actB){
  const unsigned short* x = cvt + C_X;
  const unsigned short* w = cvt + C_L0W;
  const unsigned short* b = cvt + C_L0B;
  int idx = blockIdx.x * blockDim.x + threadIdx.x;
  int n = idx >> 6, d = idx & 63;
  float acc = bf2f(b[d]);
  #pragma unroll
  for (int f = 0; f < NF; ++f) acc += bf2f(x[n*NF + f]) * bf2f(w[f*DIM + d]);
  float v = lrelu(acc);
  actF[idx] = v; actB[idx] = f2bf(v);
}

__global__ void k_u(const unsigned short* __restrict__ cvt, unsigned short* __restrict__ u){
  const unsigned short* ea = cvt + C_EA;
  const unsigned short* w  = cvt + C_NW1;
  const unsigned short* b  = cvt + C_NB1;
  int idx = blockIdx.x * blockDim.x + threadIdx.x;
  int e = idx >> 6, d = idx & 63;
  float acc = bf2f(b[d]);
  #pragma unroll
  for (int f = 0; f < 4; ++f) acc += bf2f(ea[e*4 + f]) * bf2f(w[f*DIM + d]);
  u[idx] = f2bf(lrelu(acc));
}

// big path: w2t[col][d] = net_w2[d][col]  (B^T for the ew GEMM)
__global__ void k_w2t(const unsigned short* __restrict__ cvt, unsigned short* __restrict__ w2t){
  const unsigned short* w2 = cvt + C_NW2;
  int t = blockIdx.x * blockDim.x + threadIdx.x;   // 4096*64
  int n = t >> 6, k = t & 63;
  w2t[t] = w2[k*4096 + n];
}

// fallback path: W2rT[o][k] for the rank-1 GEMM
__global__ void k_w2r(const unsigned short* __restrict__ cvt, unsigned short* __restrict__ w2rt){
  const unsigned short* w2 = cvt + C_NW2;
  const unsigned short* b2 = cvt + C_NB2;
  int t = blockIdx.x * blockDim.x + threadIdx.x;   // 64*4160
  int o = t / KTOT, k = t - o * KTOT;
  unsigned short v = (k < 4096) ? w2[(k >> 6) * 4096 + (k & 63) * 64 + o]
                                : b2[(k - 4096) * 64 + o];
  w2rt[t] = v;
}

__global__ void k_prep(const unsigned short* __restrict__ cvt,
                       unsigned short* __restrict__ crt, unsigned short* __restrict__ btg,
                       float* __restrict__ cbg, float* __restrict__ qv){
  const unsigned short* cr  = cvt + C_CRT;
  const unsigned short* wih = cvt + C_GWIH;
  const unsigned short* whh = cvt + C_GWHH;
  const unsigned short* bih = cvt + C_GBIH;
  const unsigned short* bhh = cvt + C_GBHH;
  const unsigned short* s2sbih = cvt + C_S2IH;
  const unsigned short* s2sbhh = cvt + C_S2HH;
  int tid = threadIdx.x;
  for (int t = tid; t < 4096; t += 256){ int n = t & 63, k = t >> 6; crt[n*64 + k] = cr[k*64 + n]; }
  for (int t = tid; t < 32768; t += 256){
    int nidx = t >> 7, kidx = t & 127;
    int g = nidx >> 6, d = nidx & 63, ki = kidx & 63;
    unsigned short v = 0;
    if (kidx < 64){
      if (g == 0) v = wih[ki*192 + d];
      else if (g == 1) v = wih[ki*192 + 64 + d];
      else if (g == 2) v = wih[ki*192 + 128 + d];
    } else {
      if (g == 0) v = whh[ki*192 + d];
      else if (g == 1) v = whh[ki*192 + 64 + d];
      else if (g == 3) v = whh[ki*192 + 128 + d];
    }
    btg[nidx*128 + kidx] = v;
  }
  if (tid < 256){
    int g = tid >> 6, d = tid & 63;
    float v;
    if (g == 0) v = bf2f(bih[d]) + bf2f(bhh[d]);
    else if (g == 1) v = bf2f(bih[64 + d]) + bf2f(bhh[64 + d]);
    else if (g == 2) v = bf2f(bih[128 + d]);
    else v = bf2f(bhh[128 + d]);
    cbg[tid] = v;
  }
  if (tid < 64){
    float gi = bf2f(s2sbih[tid])       + bf2f(s2sbhh[tid]);
    float gg = bf2f(s2sbih[128 + tid]) + bf2f(s2sbhh[128 + tid]);
    float go = bf2f(s2sbih[192 + tid]) + bf2f(s2sbhh[192 + tid]);
    float c = sigm(gi) * tanh_f(gg);
    qv[tid] = sigm(go) * tanh_f(c);
  }
}

// ---------------- big path: ew GEMM (once) + per-iter matvec ----------------
// ew[e][col] = sum_d z[e][d] * W2[d][col] + b2[col],  col = i*64+o

__global__ __launch_bounds__(256) void k_ew(const unsigned short* __restrict__ z,
                                            const unsigned short* __restrict__ w2t,
                                            const unsigned short* __restrict__ cvt,
                                            unsigned short* __restrict__ ew){
  const unsigned short* b2 = cvt + C_NB2;
  int w = threadIdx.x >> 6, lane = threadIdx.x & 63;
  int lm = lane & 15, q8 = (lane >> 4) * 8, rq = (lane >> 4) * 4;
  int e0 = blockIdx.x * 64;
  int n0 = blockIdx.y * 256 + w * 64;
  f32x4 acc[4][4];
  #pragma unroll
  for (int mt = 0; mt < 4; ++mt)
    #pragma unroll
    for (int nt = 0; nt < 4; ++nt) acc[mt][nt] = (f32x4){0.f, 0.f, 0.f, 0.f};
  #pragma unroll
  for (int kk = 0; kk < 2; ++kk){
    bf16x8 af[4], bfr[4];
    #pragma unroll
    for (int mt = 0; mt < 4; ++mt)
      af[mt] = *(const bf16x8*)&z[(size_t)(e0 + mt*16 + lm)*64 + kk*32 + q8];
    #pragma unroll
    for (int nt = 0; nt < 4; ++nt)
      bfr[nt] = *(const bf16x8*)&w2t[(size_t)(n0 + nt*16 + lm)*64 + kk*32 + q8];
    #pragma unroll
    for (int mt = 0; mt < 4; ++mt)
      #pragma unroll
      for (int nt = 0; nt < 4; ++nt)
        acc[mt][nt] = __builtin_amdgcn_mfma_f32_16x16x32_bf16(af[mt], bfr[nt], acc[mt][nt], 0, 0, 0);
  }
  #pragma unroll
  for (int nt = 0; nt < 4; ++nt){
    int col = n0 + nt*16 + lm;
    float bb = bf2f(b2[col]);
    #pragma unroll
    for (int mt = 0; mt < 4; ++mt)
      #pragma unroll
      for (int r = 0; r < 4; ++r){
        int row = e0 + mt*16 + rq + r;
        ew[(size_t)row*4096 + col] = f2bf(acc[mt][nt][r] + bb);
      }
  }
}

__global__ __launch_bounds__(256) void k_msg(const unsigned short* __restrict__ actB,
                                             const unsigned short* __restrict__ ew,
                                             const int* __restrict__ ei,
                                             float* __restrict__ agg){
  __shared__ float sact[4][64];
  int w = threadIdx.x >> 6, lane = threadIdx.x & 63;
  int e = blockIdx.x * 4 + w;
  int src = ei[e], dst = ei[NE + e];
  sact[w][lane] = bf2f(actB[(size_t)src*64 + lane]);
  __syncthreads();
  const unsigned short* ep = &ew[(size_t)e * 4096];
  float acc = 0.f;
  #pragma unroll 16
  for (int i = 0; i < 64; ++i) acc += sact[w][i] * bf2f(ep[i*64 + lane]);
  atomicAdd(&agg[(size_t)dst*64 + lane], acc);
}

// ---------------- fallback path: fused rank-1 message GEMM ----------------

__global__ __launch_bounds__(256) void k_msgf(const unsigned short* __restrict__ actB,
                                              const unsigned short* __restrict__ z,
                                              const unsigned short* __restrict__ w2rt,
                                              const int* __restrict__ ei,
                                              float* __restrict__ agg){
  __shared__ __align__(16) unsigned short sz[256 * 8];
  int w = threadIdx.x >> 6, lane = threadIdx.x & 63;
  int lm = lane & 15, q8 = (lane >> 4) * 8, rq = (lane >> 4) * 4;
  int e0 = blockIdx.x * 256;
  int s  = blockIdx.y;
  {
    int t = threadIdx.x;
    *(uint4*)&sz[t * 8] = *(const uint4*)&z[(size_t)(e0 + t) * 64 + s * 8];
  }
  __syncthreads();

  uint4 apack[4][2];
  #pragma unroll
  for (int mt = 0; mt < 4; ++mt){
    int src = ei[e0 + w*64 + mt*16 + lm];
    apack[mt][0] = *(const uint4*)&actB[(size_t)src * 64 + q8];
    apack[mt][1] = *(const uint4*)&actB[(size_t)src * 64 + 32 + q8];
  }

  f32x4 acc[4][4];
  #pragma unroll
  for (int mt = 0; mt < 4; ++mt)
    #pragma unroll
    for (int nt = 0; nt < 4; ++nt) acc[mt][nt] = (f32x4){0.f, 0.f, 0.f, 0.f};

  int kk0 = s * 16;
  int nk = (s == KSPLIT - 1) ? 18 : 16;
  for (int c = 0; c < nk; ++c){
    int kk = kk0 + c;
    bf16x8 bfr[4];
    #pragma unroll
    for (int nt = 0; nt < 4; ++nt)
      bfr[nt] = *(const bf16x8*)&w2rt[(size_t)(nt*16 + lm) * KTOT + kk*32 + q8];
    #pragma unroll
    for (int mt = 0; mt < 4; ++mt){
      float zf = 1.0f;
      if (kk < 128){
        int erow = w*64 + mt*16 + lm;
        zf = bf2f(sz[erow * 8 + ((kk >> 1) & 7)]);
      }
      uint4 ap = apack[mt][kk & 1];
      bf16x8 af;
      #pragma unroll
      for (int h = 0; h < 4; ++h){
        unsigned int dw = ((const unsigned int*)&ap)[h];
        float flo = __uint_as_float(dw << 16) * zf;
        float fhi = __uint_as_float(dw & 0xFFFF0000u) * zf;
        unsigned int pk = ((unsigned int)f2bf(flo)) | (((unsigned int)f2bf(fhi)) << 16);
        ((unsigned int*)&af)[h] = pk;
      }
      #pragma unroll
      for (int nt = 0; nt < 4; ++nt)
        acc[mt][nt] = __builtin_amdgcn_mfma_f32_16x16x32_bf16(af, bfr[nt], acc[mt][nt], 0, 0, 0);
    }
  }

  #pragma unroll
  for (int mt = 0; mt < 4; ++mt){
    int dstv[4];
    #pragma unroll
    for (int r = 0; r < 4; ++r) dstv[r] = ei[NE + e0 + w*64 + mt*16 + rq + r];
    #pragma unroll
    for (int nt = 0; nt < 4; ++nt)
      #pragma unroll
      for (int r = 0; r < 4; ++r)
        atomicAdd(&agg[(size_t)dstv[r] * 64 + nt*16 + lm], acc[mt][nt][r]);
  }
}

// ---------------- per-iteration: fused conv_root + GRU (4 waves / 16 nodes) ----------------

__global__ __launch_bounds__(256) void k_gru(const unsigned short* __restrict__ actB_in,
                                             const float* __restrict__ actF_in,
                                             float* __restrict__ agg, const float* __restrict__ deg,
                                             const unsigned short* __restrict__ crt,
                                             const unsigned short* __restrict__ cvt,
                                             const unsigned short* __restrict__ btg,
                                             const float* __restrict__ cbg,
                                             float* __restrict__ actF_out, unsigned short* __restrict__ actB_out){
  const unsigned short* cbias = cvt + C_CB;
  __shared__ __align__(16) unsigned short s_frag[2*4*16*8];  // [kk][q][row][j] A-fragment order
  int w = threadIdx.x >> 6, lane = threadIdx.x & 63;
  int lm = lane & 15, q = lane >> 4;
  int q8 = q*8, rq = q*4;
  int r0 = blockIdx.x * 16;
  // phase 1: wave w computes m for cols [w*16, w*16+16)
  f32x4 am = (f32x4){0.f, 0.f, 0.f, 0.f};
  #pragma unroll
  for (int kk = 0; kk < 2; ++kk){
    bf16x8 a = *(const bf16x8*)&actB_in[(size_t)(r0 + lm)*64 + kk*32 + q8];
    bf16x8 b = *(const bf16x8*)&crt[(size_t)(w*16 + lm)*64 + kk*32 + q8];
    am = __builtin_amdgcn_mfma_f32_16x16x32_bf16(a, b, am, 0, 0, 0);
  }
  {
    int col = w*16 + lm;
    float cb = bf2f(cbias[col]);
    int kk2 = w >> 1, q2 = (w & 1)*2 + (lm >> 3), j = lm & 7;
    #pragma unroll
    for (int r = 0; r < 4; ++r){
      int row = r0 + rq + r;
      float dg = fmaxf(deg[row], 1.f);
      float v = am[r] + agg[(size_t)row*64 + col] / dg + cb;
      agg[(size_t)row*64 + col] = 0.f;   // clear for next iteration
      s_frag[((kk2*4 + q2)*16 + (rq + r))*8 + j] = f2bf(lrelu(v));
    }
  }
  __syncthreads();
  // phase 2: wave w computes gate n-tiles {0,1,2,3}*64 + w*16  (r,z,inn,hn for d-cols w*16..)
  f32x4 g[4];
  #pragma unroll
  for (int t = 0; t < 4; ++t) g[t] = (f32x4){0.f, 0.f, 0.f, 0.f};
  #pragma unroll
  for (int kk = 0; kk < 4; ++kk){
    bf16x8 a;
    if (kk < 2) a = *(const bf16x8*)&s_frag[(kk*4 + q)*128 + lm*8];
    else        a = *(const bf16x8*)&actB_in[(size_t)(r0 + lm)*64 + (kk - 2)*32 + q8];
    #pragma unroll
    for (int t = 0; t < 4; ++t){
      bf16x8 b = *(const bf16x8*)&btg[(size_t)(t*64 + w*16 + lm)*128 + kk*32 + q8];
      g[t] = __builtin_amdgcn_mfma_f32_16x16x32_bf16(a, b, g[t], 0, 0, 0);
    }
  }
  {
    int d = w*16 + lm;
    float cb_r = cbg[d], cb_z = cbg[64 + d], cb_n = cbg[128 + d], cb_h = cbg[192 + d];
    #pragma unroll
    for (int r = 0; r < 4; ++r){
      int row = r0 + rq + r;
      float rr = sigm(g[0][r] + cb_r);
      float zz = sigm(g[1][r] + cb_z);
      float nn = tanh_f(g[2][r] + cb_n + rr * (g[3][r] + cb_h));
      float ho = actF_in[(size_t)row*64 + d];
      float hn2 = (1.f - zz) * nn + zz * ho;
      actF_out[(size_t)row*64 + d] = hn2;
      actB_out[(size_t)row*64 + d] = f2bf(hn2);
    }
  }
}

// ---------------- final heads ----------------

__device__ __forceinline__ int lower_bound_batch(const int* b, int val){
  int lo = 0, hi = NN;
  while (lo < hi){ int mid = (lo + hi) >> 1; if (b[mid] < val) lo = mid + 1; else hi = mid; }
  return lo;
}

__device__ __forceinline__ void store_out(void* outp, const int* flag, size_t idx, float v){
  if (*flag) ((float*)outp)[idx] = v;
  else       ((unsigned short*)outp)[idx] = f2bf(v);
}

__global__ __launch_bounds__(64) void k_graph(const float* __restrict__ act,
                                              const int* __restrict__ batch, const float* __restrict__ qv,
                                              const unsigned short* __restrict__ cvt,
                                              const int* __restrict__ flag,
                                              void* __restrict__ outp){
  const unsigned short* lw = cvt + C_LOW;
  const unsigned short* lb = cvt + C_LOB;
  __shared__ float se[512];
  int b = blockIdx.x, lane = threadIdx.x;
  int lo = lower_bound_batch(batch, b);
  int hi = lower_bound_batch(batch, b + 1);
  int cnt = hi - lo; if (cnt > 512) cnt = 512;
  float qvl = qv[lane];
  for (int ii = 0; ii < cnt; ++ii){
    float p = act[(size_t)(lo + ii)*64 + lane] * qvl;
    p = wred_sum(p);
    if (lane == 0) se[ii] = p;
  }
  __syncthreads();
  float em = -3.4e38f;
  for (int ii = lane; ii < cnt; ii += 64) em = fmaxf(em, se[ii]);
  em = wred_max(em);
  float sm = 0.f;
  for (int ii = lane; ii < cnt; ii += 64) sm += __expf(se[ii] - em);
  float denom = wred_sum(sm);
  float rp = 0.f;
  for (int ii = 0; ii < cnt; ++ii) rp += __expf(se[ii] - em) * act[(size_t)(lo + ii)*64 + lane];
  if (cnt > 0 && denom > 0.f) rp /= denom;
  float s0 = qvl*bf2f(lw[lane*2])     + rp*bf2f(lw[(64 + lane)*2]);
  float s1 = qvl*bf2f(lw[lane*2 + 1]) + rp*bf2f(lw[(64 + lane)*2 + 1]);
  s0 = wred_sum(s0); s1 = wred_sum(s1);
  if (lane == 0){
    store_out(outp, flag, b*2,     s0 + bf2f(lb[0]));
    store_out(outp, flag, b*2 + 1, s1 + bf2f(lb[1]));
  }
}

__global__ __launch_bounds__(256) void k_stem(const float* __restrict__ act, const int* __restrict__ sidx,
                                              const unsigned short* __restrict__ cvt,
                                              const int* __restrict__ flag,
                                              void* __restrict__ outp){
  const unsigned short* w1 = cvt + C_SW1;
  const unsigned short* b1 = cvt + C_SB1;
  const unsigned short* w2 = cvt + C_SW2;
  const unsigned short* b2 = cvt + C_SB2;
  __shared__ float sa[4][64], st[4][64];
  int w = threadIdx.x >> 6, lane = threadIdx.x & 63;
  int s = blockIdx.x * 4 + w;
  int a = sidx[s];
  sa[w][lane] = act[(size_t)a*64 + lane];
  __syncthreads();
  float t = bf2f(b1[lane]);
  #pragma unroll 8
  for (int i = 0; i < 64; ++i) t += sa[w][i] * bf2f(w1[i*64 + lane]);
  st[w][lane] = lrelu(t);
  __syncthreads();
  size_t base = 512 + (size_t)s * NOUT;
  float v = bf2f(b2[lane]);
  #pragma unroll 8
  for (int d = 0; d < 64; ++d) v += st[w][d] * bf2f(w2[d*NOUT + lane]);
  store_out(outp, flag, base + lane, v);
  int o2 = 64 + lane;
  if (o2 < NOUT){
    float v2 = bf2f(b2[o2]);
    #pragma unroll 8
    for (int d = 0; d < 64; ++d) v2 += st[w][d] * bf2f(w2[d*NOUT + o2]);
    store_out(outp, flag, base + o2, v2);
  }
}

__global__ __launch_bounds__(256) void k_jbond(const float* __restrict__ act, const int* __restrict__ jidx,
                                               const unsigned short* __restrict__ cvt,
                                               const int* __restrict__ flag,
                                               void* __restrict__ outp){
  const unsigned short* w1 = cvt + C_JW1;
  const unsigned short* b1 = cvt + C_JB1;
  const unsigned short* w2 = cvt + C_JW2;
  const unsigned short* b2 = cvt + C_JB2;
  __shared__ float a0[4][64], a1[4][64];
  int w = threadIdx.x >> 6, lane = threadIdx.x & 63;
  int j = blockIdx.x * 4 + w;
  int i0 = jidx[j*2], i1 = jidx[j*2 + 1];
  a0[w][lane] = act[(size_t)i0*64 + lane];
  a1[w][lane] = act[(size_t)i1*64 + lane];
  __syncthreads();
  float t0 = bf2f(b1[lane]), t1 = t0;
  #pragma unroll 8
  for (int i = 0; i < 64; ++i){
    float wv = bf2f(w1[i*64 + lane]);
    t0 += a0[w][i] * wv;
    t1 += a1[w][i] * wv;
  }
  t0 = lrelu(t0); t1 = lrelu(t1);
  float p = (t0 + t1) * bf2f(w2[lane]);
  p = wred_sum(p);
  if (lane == 0) store_out(outp, flag, 512 + (size_t)NS*NOUT + j, 0.5f * p + bf2f(b2[0]));
}

// ---------------- launcher ----------------

extern "C" void kernel_launch(void* const* d_in, const int* in_sizes, int n_in,
                              void* d_out, int out_size, void* d_ws, size_t ws_size,
                              hipStream_t stream){
  (void)in_sizes; (void)n_in; (void)out_size;
  const int* edge_index = (const int*)d_in[2];
  const int* batch      = (const int*)d_in[3];
  const int* stem_idx   = (const int*)d_in[4];
  const int* jbond_idx  = (const int*)d_in[5];

  char* ws = (char*)d_ws;
  size_t off = 0;
  auto alloc = [&](size_t bytes) -> void* {
    void* p = ws + off; off += (bytes + 255) & ~(size_t)255; return p;
  };
  unsigned short* cvt  = (unsigned short*)alloc((size_t)C_TOT * 2);
  unsigned short* w2t  = (unsigned short*)alloc((size_t)4096 * 64 * 2);
  unsigned short* w2rt = (unsigned short*)alloc((size_t)64 * KTOT * 2);
  unsigned short* z_bf = (unsigned short*)alloc((size_t)NE * 64 * 2);
  float* actF0 = (float*)alloc((size_t)NN * 64 * 4);
  float* actF1 = (float*)alloc((size_t)NN * 64 * 4);
  unsigned short* actB0 = (unsigned short*)alloc((size_t)NN * 64 * 2);
  unsigned short* actB1 = (unsigned short*)alloc((size_t)NN * 64 * 2);
  float* deg  = (float*)alloc(NN * 4);
  float* agg  = (float*)alloc((size_t)NN * 64 * 4);   // contiguous after deg: one memset
  unsigned short* crt = (unsigned short*)alloc(64 * 64 * 2);
  unsigned short* btg = (unsigned short*)alloc(256 * 128 * 2);
  float* cbg  = (float*)alloc(256 * 4);
  float* qv   = (float*)alloc(64 * 4);
  int* flag   = (int*)alloc(256);
  size_t ew_bytes = (size_t)NE * 4096 * 2;   // 134 MB
  bool big = (off + ew_bytes) <= ws_size;
  unsigned short* ew = big ? (unsigned short*)alloc(ew_bytes) : nullptr;

  // deg + agg are adjacent: single memset covers both (agg self-clears in k_gru thereafter)
  hipMemsetAsync(deg, 0, ((size_t)NN * 4) + ((size_t)NN * 64 * 4) + 256, stream);

  k_detect<<<1, 256, 0, stream>>>((const unsigned short*)d_in[1], flag);

  CvtArgs ca;
  const int srcIdx[26] = {0,1,6,7,8,9,10,11,12,13,14,15,16,17,18,19,20,21,22,23,24,25,28,29,30,31};
  const int ns[26]  = {114688,65536,896,64,256,64,262144,4096,4096,64,12288,12288,192,192,
                       4096,64,6720,105,4096,64,64,1,256,256,256,2};
  const int ofs[26] = {C_X,C_EA,C_L0W,C_L0B,C_NW1,C_NB1,C_NW2,C_NB2,C_CRT,C_CB,C_GWIH,C_GWHH,
                       C_GBIH,C_GBHH,C_SW1,C_SB1,C_SW2,C_SB2,C_JW1,C_JB1,C_JW2,C_JB2,
                       C_S2IH,C_S2HH,C_LOW,C_LOB};
  for (int j = 0; j < 26; ++j){ ca.src[j] = d_in[srcIdx[j]]; ca.n[j] = ns[j]; ca.off[j] = ofs[j]; }
  k_cvt<<<512, 256, 0, stream>>>(ca, flag, cvt);

  k_deg<<<NE/256, 256, 0, stream>>>(edge_index, deg);
  k_lin0<<<NN*DIM/256, 256, 0, stream>>>(cvt, actF0, actB0);
  k_u<<<NE*DIM/256, 256, 0, stream>>>(cvt, z_bf);
  k_prep<<<1, 256, 0, stream>>>(cvt, crt, btg, cbg, qv);

  if (big){
    k_w2t<<<4096*64/256, 256, 0, stream>>>(cvt, w2t);
    k_ew<<<dim3(NE/64, 16), 256, 0, stream>>>(z_bf, w2t, cvt, ew);
  } else {
    k_w2r<<<64*KTOT/256, 256, 0, stream>>>(cvt, w2rt);
  }

  for (int t = 0; t < 6; ++t){
    const float* aF_in  = (t & 1) ? actF1 : actF0;
    float* aF_out       = (t & 1) ? actF0 : actF1;
    const unsigned short* aB_in = (t & 1) ? actB1 : actB0;
    unsigned short* aB_out      = (t & 1) ? actB0 : actB1;
    if (big)
      k_msg<<<NE/4, 256, 0, stream>>>(aB_in, ew, edge_index, agg);
    else
      k_msgf<<<dim3(NE/256, KSPLIT), 256, 0, stream>>>(aB_in, z_bf, w2rt, edge_index, agg);
    k_gru<<<NN/16, 256, 0, stream>>>(aB_in, aF_in, agg, deg, crt, cvt, btg, cbg,
                                     aF_out, aB_out);
  }
  k_graph<<<NB, 64, 0, stream>>>(actF0, batch, qv, cvt, flag, d_out);
  k_stem<<<NS/4, 256, 0, stream>>>(actF0, stem_idx, cvt, flag, d_out);
  k_jbond<<<NJ/4, 256, 0, stream>>>(actF0, jbond_idx, cvt, flag, d_out);
}